// Round 14
// baseline (2710.345 us; speedup 1.0000x reference)
//
#include <hip/hip_runtime.h>
#include <hip/hip_bf16.h>
#include <stdint.h>

typedef uint32_t u32;

#define DELTAF 1e-6f

__device__ __forceinline__ float bl(u32 u) { return __uint_as_float(u << 16); }
__device__ __forceinline__ float bh(u32 u) { return __uint_as_float(u & 0xffff0000u); }

// ---- fast transcendentals (f32 in/out, ~1e-7 rel err; deterministic) ----
__device__ __forceinline__ float fexp(float x) { return __builtin_amdgcn_exp2f(x * 1.4426950408889634f); }
__device__ __forceinline__ float frcp(float x) { return __builtin_amdgcn_rcpf(x); }
__device__ __forceinline__ float fsig(float x) { return frcp(1.f + fexp(-x)); }
__device__ __forceinline__ float ftanh(float x) {
  float xx = fminf(fmaxf(x, -15.f), 15.f);
  float t = __builtin_amdgcn_exp2f(xx * 2.8853900817779268f);  // e^(2x)
  return (t - 1.f) * frcp(t + 1.f);
}
__device__ __forceinline__ float softplusf(float x) { return fmaxf(x, 0.f) + log1pf(expf(-fabsf(x))); }

// f32 -> bf16 bits, RNE
__device__ __forceinline__ u32 f2b(float f) {
  u32 b = __float_as_uint(f);
  return (b + 0x7fffu + ((b >> 16) & 1u)) >> 16;
}
__device__ __forceinline__ u32 pk2(float a, float b) { return f2b(a) | (f2b(b) << 16); }

// ---- DPP reduction helpers (VALU-only) ----
template<int CTRL>
__device__ __forceinline__ float dppf(float v) {
  return __int_as_float(__builtin_amdgcn_update_dpp(0, __float_as_int(v), CTRL, 0xf, 0xf, true));
}
__device__ __forceinline__ float dsum16(float v) {
  v += dppf<0x128>(v); v += dppf<0x124>(v); v += dppf<0x122>(v); v += dppf<0x121>(v);
  return v;
}
__device__ __forceinline__ float dmax16(float v) {
  v = fmaxf(v, dppf<0x128>(v)); v = fmaxf(v, dppf<0x124>(v));
  v = fmaxf(v, dppf<0x122>(v)); v = fmaxf(v, dppf<0x121>(v));
  return v;
}
__device__ __forceinline__ float dsum4(float v) {
  v += dppf<0xB1>(v); v += dppf<0x4E>(v);
  return v;
}
__device__ __forceinline__ float rdlane(float v, int lane) {
  return __int_as_float(__builtin_amdgcn_readlane(__float_as_int(v), lane));
}

// load 64 consecutive f32 -> bf16 RNE, pack into 32 u32 (registers)
__device__ __forceinline__ void ldrow64pk(u32* w, const float* p) {
  const float4* q = (const float4*)p;
#pragma unroll
  for (int i = 0; i < 16; ++i) {
    float4 v = q[i];
    w[2*i]   = pk2(v.x, v.y);
    w[2*i+1] = pk2(v.z, v.w);
  }
}

// load 128 consecutive f32 -> bf16 RNE, pack pairs into 64 u32
__device__ __forceinline__ void ldrow128pk(u32* w, const float* p) {
  const float4* q = (const float4*)p;
#pragma unroll
  for (int i = 0; i < 32; ++i) {
    float4 v = q[i];
    w[2*i]   = pk2(v.x, v.y);
    w[2*i+1] = pk2(v.z, v.w);
  }
}

// 64-long dot, packed bf16 weights (32 u32), x from LDS (broadcast reads)
__device__ __forceinline__ float dotp64(const u32* w, const float* x) {
  float a0 = 0.f, a1 = 0.f;
#pragma unroll
  for (int i = 0; i < 8; ++i) {
    float4 v0 = ((const float4*)x)[2*i+0];
    float4 v1 = ((const float4*)x)[2*i+1];
    u32 p0 = w[4*i+0], q0 = w[4*i+1], p1 = w[4*i+2], q1 = w[4*i+3];
    a0 = fmaf(bl(p0), v0.x, a0); a0 = fmaf(bh(p0), v0.y, a0);
    a0 = fmaf(bl(q0), v0.z, a0); a0 = fmaf(bh(q0), v0.w, a0);
    a1 = fmaf(bl(p1), v1.x, a1); a1 = fmaf(bh(p1), v1.y, a1);
    a1 = fmaf(bl(q1), v1.z, a1); a1 = fmaf(bh(q1), v1.w, a1);
  }
  return a0 + a1;
}

// 128-long dot, packed bf16 weights in regs, x from LDS
__device__ __forceinline__ float dotp128(const u32* w, const float* x) {
  float a0 = 0.f, a1 = 0.f, a2 = 0.f, a3 = 0.f;
#pragma unroll
  for (int i = 0; i < 8; ++i) {
    float4 v0 = ((const float4*)x)[4*i+0];
    float4 v1 = ((const float4*)x)[4*i+1];
    float4 v2 = ((const float4*)x)[4*i+2];
    float4 v3 = ((const float4*)x)[4*i+3];
    u32 p0 = w[8*i+0], q0 = w[8*i+1], p1 = w[8*i+2], q1 = w[8*i+3];
    u32 p2 = w[8*i+4], q2 = w[8*i+5], p3 = w[8*i+6], q3 = w[8*i+7];
    a0 = fmaf(bl(p0), v0.x, a0); a0 = fmaf(bh(p0), v0.y, a0);
    a0 = fmaf(bl(q0), v0.z, a0); a0 = fmaf(bh(q0), v0.w, a0);
    a1 = fmaf(bl(p1), v1.x, a1); a1 = fmaf(bh(p1), v1.y, a1);
    a1 = fmaf(bl(q1), v1.z, a1); a1 = fmaf(bh(q1), v1.w, a1);
    a2 = fmaf(bl(p2), v2.x, a2); a2 = fmaf(bh(p2), v2.y, a2);
    a2 = fmaf(bl(q2), v2.z, a2); a2 = fmaf(bh(q2), v2.w, a2);
    a3 = fmaf(bl(p3), v3.x, a3); a3 = fmaf(bh(p3), v3.y, a3);
    a3 = fmaf(bl(q3), v3.z, a3); a3 = fmaf(bh(q3), v3.w, a3);
  }
  return (a0 + a1) + (a2 + a3);
}

// dot over 4*n4 elements, f32 weights streamed from global
__device__ __forceinline__ float dotgf(const float* row, const float* x, int n4) {
  float a = 0.f;
  for (int i = 0; i < n4; ++i) {
    float4 w = ((const float4*)row)[i];
    float4 xv = ((const float4*)x)[i];
    a = fmaf(w.x, xv.x, a);
    a = fmaf(w.y, xv.y, a);
    a = fmaf(w.z, xv.z, a);
    a = fmaf(w.w, xv.w, a);
  }
  return a;
}

// ---------------- prep kernels (gi_emb precompute) ----------------
__global__ void prep_enc(const float* __restrict__ emb, const int* __restrict__ seq,
                         const float* __restrict__ Wih, const float* __restrict__ bih,
                         float* __restrict__ giE)
{
  __shared__ __align__(16) float sx[64];
  const int it = blockIdx.x, t = threadIdx.x;
  if (t < 64) sx[t] = emb[(size_t)seq[it]*64 + t];
  __syncthreads();
  if (t < 192) giE[it*192 + t] = bih[t] + dotgf(Wih + (size_t)t*128, sx, 16);
}

__global__ void prep_dec(const float* __restrict__ emb2, const int* __restrict__ seq3,
                         const float* __restrict__ Wih, const float* __restrict__ bih,
                         float* __restrict__ giE)
{
  __shared__ __align__(16) float sx[64];
  const int it = blockIdx.x, t = threadIdx.x;
  const int tok = (it == 0) ? 136 : seq3[it-1];
  if (t < 64) sx[t] = emb2[(size_t)tok*64 + t];
  __syncthreads();
  if (t < 384) giE[it*384 + t] = bih[t] + dotgf(Wih + (size_t)t*192, sx, 16);
}

// ---------------- pack: dec Whh^T + ifw^T, bf16-pair [k2][r] ----------------
__global__ void pack_weights(const float* __restrict__ dWhh, const float* __restrict__ ifwW,
                             float* __restrict__ pk)
{
  const int i = blockIdx.x * 256 + threadIdx.x;
  u32* pku = (u32*)pk;
  if (i < 24576) {
    int r = i >> 6, k2 = i & 63;
    pku[k2*384 + r] = pk2(dWhh[r*128 + 2*k2], dWhh[r*128 + 2*k2 + 1]);
  } else if (i < 33280) {
    int p = i - 24576;
    int r = p >> 6, k2 = p & 63;
    pku[24576 + k2*136 + r] = pk2(ifwW[r*128 + 2*k2], ifwW[r*128 + 2*k2 + 1]);
  }
}

// ---------------- encoder: 512 sequential DNC steps, 1 block per encoder (R13 frozen) ----------------
// stout per encoder (1440 f32):
//  [0,64) h | [64,128) lr | [128,144) rw | [144,160) mem norms | [160,1184) mem | [1184,1440) link
__global__ __launch_bounds__(512) void enc_kernel(
    const float* __restrict__ Wih1, const float* __restrict__ Whh1, const float* __restrict__ bhh1,
    const float* __restrict__ iW1, const float* __restrict__ ib1,
    const float* __restrict__ Wih2, const float* __restrict__ Whh2, const float* __restrict__ bhh2,
    const float* __restrict__ iW2, const float* __restrict__ ib2,
    const float* __restrict__ giE_all, float* __restrict__ stout)
{
  __shared__ __align__(16) float s_giE[64*192];   // 64-step gi_emb chunk (49 KB)
  __shared__ __align__(16) float s_h[64];
  __shared__ __align__(16) float s_lr[64];
  __shared__ float s_gi[192];
  __shared__ float s_ghb[2][192];                 // gh pipeline (double buffer)
  __shared__ float s_xi[264];
  __shared__ float s_mem[16][65];                 // padded: conflict-free
  __shared__ float s_link[16][16];
  __shared__ float s_prec[2][16];
  __shared__ float s_rw[16], s_ww[16], s_usage[16];
  __shared__ float s_norm[16], s_sim[16], s_fw[16];
  __shared__ float s_rk[64], s_ev[64], s_wv[64];  // hoisted activations
  __shared__ float s_sc[8]; // 0:rs 1:ws 3:ag 4:wg 5..7:rm
  __shared__ float s_wkn, s_rkn;

  const int t = threadIdx.x;
  const int e = blockIdx.x;
  const float* Wih = e ? Wih2 : Wih1;
  const float* Whh = e ? Whh2 : Whh1;
  const float* bhh = e ? bhh2 : bhh1;
  const float* iW  = e ? iW2  : iW1;
  const float* ib  = e ? ib2  : ib1;
  const float* giE = giE_all + (size_t)e * 512 * 192;

  // register weights: wA = gi rows (t<192); w2 = xi rows (t<264) OR gh rows (264<=t<456)
  u32 wA[32], w2[32];
  float b2 = 0.f;
  if (t < 192) ldrow64pk(wA, Wih + (size_t)t*128 + 64);
  if (t < 264)      { ldrow64pk(w2, iW + (size_t)t*64);        b2 = ib[t]; }
  else if (t < 456) { ldrow64pk(w2, Whh + (size_t)(t-264)*64); b2 = bhh[t-264]; }

  if (t < 192) s_ghb[0][t] = bhh[t];     // h0 = 0 -> gh(step0) = bhh
  if (t < 64) { s_h[t] = 0.f; s_lr[t] = 0.f; }
  if (t < 16) {
    s_rw[t] = DELTAF; s_ww[t] = DELTAF; s_usage[t] = 0.f; s_norm[t] = 0.f;
    s_prec[0][t] = 0.f; s_prec[1][t] = 0.f;
  }
  for (int i = t; i < 1040; i += 512) { int m = i / 65, c = i % 65; s_mem[m][c] = 0.f; }
  if (t < 256) (&s_link[0][0])[t] = 0.f;
  __syncthreads();

  int pb = 0;
  for (int it = 0; it < 512; ++it) {
    // ---- chunk refill (8x total, only global access) ----
    if ((it & 63) == 0) {
      const float4* src = (const float4*)(giE + it*192);
      float4* dst = (float4*)s_giE;
      for (int i = t; i < 3072; i += 512) dst[i] = src[i];
      __syncthreads();
    }
    // ---- P1: gi GEMV (reg weights, lr broadcast from LDS) ----
    if (t < 192) s_gi[t] = s_giE[(it & 63)*192 + t] + dotp64(wA, s_lr);
    __syncthreads();
    // ---- P2: GRU combine (gh from pipeline; clip removed: |h|<=1 so CLIP(20) is a no-op) ----
    if (t < 64) {
      const float* ghb = s_ghb[it & 1];
      float r = fsig(s_gi[t] + ghb[t]);
      float z = fsig(s_gi[64+t] + ghb[64+t]);
      float n = ftanh(s_gi[128+t] + r*ghb[128+t]);
      s_h[t] = (1.f - z)*n + z*s_h[t];
    }
    __syncthreads();
    // ---- P3: xi GEMV (t<264) || gh GEMV for NEXT step (264<=t<456) ----
    if (t < 264)      s_xi[t] = b2 + dotp64(w2, s_h);
    else if (t < 456) s_ghb[(it + 1) & 1][t - 264] = b2 + dotp64(w2, s_h);
    __syncthreads();
    // ---- S1: write-key sim (16-lane DPP) + norms (16-lane DPP) + usage + scalars + hoists ----
    {
      int m = (t >> 4) & 15, l = t & 15;
      float p = 0.f;
#pragma unroll
      for (int i = 0; i < 4; ++i) {
        int el = l*4 + i;
        float wk = ftanh(s_xi[65+el]);
        p = fmaf(wk, s_mem[m][el], p);
      }
      p = dsum16(p);
      if (l == 0 && t < 256) s_sim[m] = p;   // raw dot; normalized later
    }
    if (t < 64) {
      s_ev[t] = fsig(s_xi[130+t]);
    } else if (t < 80) {                      // read-key norm (16 lanes x 4 elems)
      int l = t - 64;
      float q = 0.f;
#pragma unroll
      for (int i = 0; i < 4; ++i) { float v = ftanh(s_xi[l*4+i]); q = fmaf(v, v, q); }
      q = dsum16(q);
      if (t == 64) s_rkn = sqrtf(q);
    } else if (t < 96) {                      // write-key norm
      int l = t - 80;
      float q = 0.f;
#pragma unroll
      for (int i = 0; i < 4; ++i) { float v = ftanh(s_xi[65 + l*4+i]); q = fmaf(v, v, q); }
      q = dsum16(q);
      if (t == 80) s_wkn = sqrtf(q);
    } else if (t >= 192 && t < 208) {
      int j = t - 192;                        // usage update (prev ww, prev rw, this fg)
      float fg = fsig(s_xi[258]);
      float u = s_usage[j];
      u = u + (1.f - u) * s_ww[j];
      u = u * (1.f - fg * s_rw[j]);
      s_usage[j] = u;
    } else if (t == 208) s_sc[0] = softplusf(s_xi[64]);
    else if (t == 209) s_sc[1] = softplusf(s_xi[129]);
    else if (t == 210) s_sc[3] = fsig(s_xi[259]);
    else if (t == 211) s_sc[4] = fsig(s_xi[260]);
    else if (t == 212) {
      float a = s_xi[261], b = s_xi[262], c = s_xi[263];
      float mx = fmaxf(a, fmaxf(b, c));
      float ea = fexp(a-mx), eb = fexp(b-mx), ec = fexp(c-mx);
      float s = frcp(ea + eb + ec);
      s_sc[5] = ea*s; s_sc[6] = eb*s; s_sc[7] = ec*s;
    } else if (t >= 384 && t < 448) {
      int l = t - 384;                        // hoisted read-key tanh
      s_rk[l] = ftanh(s_xi[l]);
    } else if (t >= 448) {
      int l = t - 448;                        // hoisted write-vector tanh
      s_wv[l] = ftanh(s_xi[194+l]);
    }
    __syncthreads();
    // ---- S23: per-row redundant write-softmax/alloc (DPP); mem write (readlane); link+fw; prec ----
    {
      int row = t & 15;
      float x = s_sim[row] * frcp((s_norm[row] + DELTAF) * (s_wkn + DELTAF)) * s_sc[1];
      float mx = dmax16(x);
      float ex = fexp(x - mx);
      float sm = dsum16(ex);
      float wcw = ex * frcp(sm);
      float um = DELTAF + (1.f - DELTAF) * s_usage[row];
      float prod = 1.f;
#pragma unroll
      for (int j = 0; j < 16; ++j) {
        float v = DELTAF + (1.f - DELTAF) * s_usage[j];
        bool before = (v < um) || ((v == um) && (j < row));  // stable argsort order
        prod *= before ? v : 1.f;
      }
      float alloc = (1.f - um) * prod;
      float wwv = s_sc[4] * (s_sc[3]*alloc + (1.f - s_sc[3])*wcw);
      float S = dsum16(wwv);
      if (t < 16) s_ww[t] = wwv;              // for next step's usage update
      // memory write: m uniform per wave per q -> readlane broadcast (SALU)
#pragma unroll
      for (int q = 0; q < 2; ++q) {
        int idx = t + q*512;
        int m = idx >> 6, wi = idx & 63;
        float wwm = rdlane(wwv, m);
        s_mem[m][wi] = s_mem[m][wi] * (1.f - wwm * s_ev[wi]) + wwm * s_wv[wi];
      }
      if (t < 256) {                          // link + fw (waves 0..3)
        int i = t >> 4, j = t & 15;           // j == row
        float wwi = __shfl(wwv, i);           // per-lane gather (keep, 1 ds op)
        float lv = (i == j) ? 0.f
                 : ((1.f - wwi - wwv) * s_link[i][j] + wwi * s_prec[pb][j]);
        s_link[i][j] = lv;
        float p = dsum16(lv * s_rw[j]);
        if (j == 0) s_fw[i] = p;
      } else if (t < 272) {                   // precedence (wave 4, lanes 0..15)
        int j = t - 256;                      // == row
        s_prec[pb^1][j] = (1.f - S) * s_prec[pb][j] + wwv;
      }
    }
    __syncthreads();
    // ---- S45: wave-0 mega-phase: read sim+norm (quad DPP) + bw + softmax (DPP) + rw + lr ----
    if (t < 64) {
      int l = t;
      int r4 = l >> 2, seg = l & 3;
      float p = 0.f, q = 0.f;
#pragma unroll
      for (int i = 0; i < 16; ++i) {
        int el = seg*16 + i;
        float mv = s_mem[r4][el];
        p = fmaf(s_rk[el], mv, p);
        q = fmaf(mv, mv, q);
      }
      p = dsum4(p); q = dsum4(q);
      int row = l & 15;
      float simv  = __shfl(p, 4*row);          // fixed permutation gather
      float normv = sqrtf(__shfl(q, 4*row));
      float b = 0.f;                           // bw_row, partial over j
#pragma unroll
      for (int jj = 0; jj < 4; ++jj) {
        int j = (l >> 4)*4 + jj;
        b = fmaf(s_link[j][row], s_rw[j], b);
      }
      b += __shfl_xor(b,16); b += __shfl_xor(b,32);
      float x = simv * frcp((normv + DELTAF) * (s_rkn + DELTAF)) * s_sc[0];
      float mx = dmax16(x);
      float ex = fexp(x - mx);
      float sm = dsum16(ex);
      float cw = ex * frcp(sm);
      float rwv = s_sc[5]*b + s_sc[6]*s_fw[row] + s_sc[7]*cw;
      if (l < 16) { s_rw[l] = rwv; s_norm[l] = normv; }   // norm carried to next step
      float a = 0.f;
#pragma unroll
      for (int m = 0; m < 16; ++m) a = fmaf(rdlane(rwv, m), s_mem[m][l], a);
      s_lr[l] = a;
    }
    pb ^= 1;
    __syncthreads();
  }

  float* so = stout + (size_t)e * 1440;
  if (t < 64) { so[t] = s_h[t]; so[64+t] = s_lr[t]; }
  if (t < 16) { so[128+t] = s_rw[t]; so[144+t] = s_norm[t]; }
  for (int i = t; i < 1024; i += 512) { int m = i >> 6, c = i & 63; so[160+i] = s_mem[m][c]; }
  if (t < 256) so[1184+t] = (&s_link[0][0])[t];
}

// ---------------- decoder: 65 steps; Wih in regs, ifw in LDS, Whh in LDS (152 KB total) ----------------
__global__ __launch_bounds__(512) void dec_kernel(
    const float* __restrict__ bhh, const float* __restrict__ ifwb,
    const float* __restrict__ dWih,
    const float* __restrict__ giE, const float* __restrict__ st,
    const float* __restrict__ pk, float* __restrict__ r12h)
{
  __shared__ u32 s_Whh[24576];                 // Whh^T bf16-pair [k2][r] (96 KB, LDS-resident)
  __shared__ u32 s_pIfw[8704];                 // ifw^T bf16-pair [k2][r] (34 KB)
  __shared__ __align__(16) float s_h[128];
  __shared__ __align__(16) float s_r12[128];
  __shared__ float s_gi[384], s_ghb[2][384], s_xi[136];
  __shared__ __align__(16) float s_mem[2][16][64];
  __shared__ float s_link[2][16][16];
  __shared__ float s_rw[2][16], s_norm[2][16];
  __shared__ float s_sim[2][16], s_fw[2][16], s_bw[2][16];
  __shared__ float s_rs[2], s_rkn[2];
  __shared__ float s_rm[2][3];
  __shared__ float s_bhh[384], s_ifwb[136];

  const int t = threadIdx.x;
  const u32* pWhh = (const u32*)pk;            // [k2*384 + r]
  const u32* pIfw = (const u32*)pk + 24576;    // [k2*136 + r]

  u32 w1[64];                                  // Wih-x row t (t<384), bf16
  if (t < 384) ldrow128pk(w1, dWih + (size_t)t*192 + 64);

  for (int i = t; i < 24576; i += 512) s_Whh[i] = pWhh[i];
  for (int i = t; i < 8704; i += 512) s_pIfw[i] = pIfw[i];
  if (t < 384) s_bhh[t]  = bhh[t];
  if (t < 136) s_ifwb[t] = ifwb[t];
  if (t < 64) {
    s_h[t]      = st[t];        s_h[64+t]   = st[1440+t];
    s_r12[t]    = st[64+t];     s_r12[64+t] = st[1440+64+t];
  }
  if (t < 16) {
    s_rw[0][t]   = st[128+t];   s_rw[1][t]   = st[1440+128+t];
    s_norm[0][t] = st[144+t];   s_norm[1][t] = st[1440+144+t];
  }
  for (int i = t; i < 1024; i += 512) {
    (&s_mem[0][0][0])[i] = st[160+i];
    (&s_mem[1][0][0])[i] = st[1440+160+i];
  }
  if (t < 256) {
    (&s_link[0][0][0])[t] = st[1184+t];
    (&s_link[1][0][0])[t] = st[1440+1184+t];
  }
  __syncthreads();

  // prologue: gh(step 0) = bhh + Whh . h0 (from LDS)
  if (t < 384) {
    float a = 0.f;
#pragma unroll 8
    for (int k2 = 0; k2 < 64; ++k2) {
      u32 wp = s_Whh[k2*384 + t];
      float2 xh = *(const float2*)&s_h[2*k2];
      a = fmaf(bl(wp), xh.x, fmaf(bh(wp), xh.y, a));
    }
    s_ghb[0][t] = s_bhh[t] + a;
  }
  __syncthreads();

  float gcur = (t < 384) ? giE[t] : 0.f;

  for (int it = 0; it < 65; ++it) {
    // ---- P1: gi (reg weights, x=[r1;r2]) ----
    if (t < 384) {
      int nx = (it + 1 < 65) ? (it + 1) : 64;
      float gn = giE[nx*384 + t];
      s_gi[t] = gcur + dotp128(w1, s_r12);
      gcur = gn;
    }
    __syncthreads();
    // ---- P2: GRU (H=128), gh from pipeline ----
    if (t < 128) {
      const float* ghb = s_ghb[it & 1];
      float r = fsig(s_gi[t] + ghb[t]);
      float z = fsig(s_gi[128+t] + ghb[128+t]);
      float n = ftanh(s_gi[256+t] + r*ghb[256+t]);
      s_h[t] = (1.f - z)*n + z*s_h[t];
    }
    __syncthreads();
    // ---- P3: gh(next) from LDS Whh (t<384) || xi from LDS ifw (t>=384) ----
    if (t < 384) {
      float a = 0.f;
#pragma unroll 8
      for (int k2 = 0; k2 < 64; ++k2) {
        u32 wp = s_Whh[k2*384 + t];
        float2 xh = *(const float2*)&s_h[2*k2];
        a = fmaf(bl(wp), xh.x, fmaf(bh(wp), xh.y, a));
      }
      s_ghb[(it + 1) & 1][t] = s_bhh[t] + a;
    } else {
      int r0 = t - 384;
      float c0 = 0.f;
#pragma unroll 8
      for (int k2 = 0; k2 < 64; ++k2) {
        u32 u = s_pIfw[k2*136 + r0];
        float2 xh = *(const float2*)&s_h[2*k2];
        c0 = fmaf(bl(u), xh.x, fmaf(bh(u), xh.y, c0));
      }
      s_xi[r0] = s_ifwb[r0] + c0;
      if (r0 < 8) {
        int r1 = 128 + r0;
        float c1 = 0.f;
#pragma unroll 8
        for (int k2 = 0; k2 < 64; ++k2) {
          u32 u = s_pIfw[k2*136 + r1];
          float2 xh = *(const float2*)&s_h[2*k2];
          c1 = fmaf(bl(u), xh.x, fmaf(bh(u), xh.y, c1));
        }
        s_xi[r1] = s_ifwb[r1] + c1;
      }
    }
    __syncthreads();
    // ---- S1: per-half sim (raw) + rk norm + fw/bw + scalars ----
    {
      int half = t >> 8, u = t & 255;
      int m = u >> 4, l = u & 15;
      float p = 0.f;
#pragma unroll
      for (int i = 0; i < 4; ++i) {
        float rk = ftanh(s_xi[half*64 + l*4 + i]);
        p = fmaf(rk, s_mem[half][m][l*4+i], p);
      }
      p += __shfl_xor(p,1); p += __shfl_xor(p,2); p += __shfl_xor(p,4); p += __shfl_xor(p,8);
      if (l == 0) s_sim[half][m] = p;
      if (u < 64) {
        float v = ftanh(s_xi[half*64 + u]);
        float q = v*v;
        q += __shfl_xor(q,1); q += __shfl_xor(q,2); q += __shfl_xor(q,4);
        q += __shfl_xor(q,8); q += __shfl_xor(q,16); q += __shfl_xor(q,32);
        if (u == 0) s_rkn[half] = sqrtf(q);
      } else if (u < 80) {
        int i = u - 64;
        float a = 0.f;
#pragma unroll
        for (int j = 0; j < 16; ++j) a = fmaf(s_link[half][i][j], s_rw[half][j], a);
        s_fw[half][i] = a;
      } else if (u < 96) {
        int i = u - 80;
        float a = 0.f;
#pragma unroll
        for (int j = 0; j < 16; ++j) a = fmaf(s_link[half][j][i], s_rw[half][j], a);
        s_bw[half][i] = a;
      } else if (u == 96) {
        s_rs[half] = softplusf(s_xi[128 + half]);
        float a = s_xi[130 + half*3], b = s_xi[131 + half*3], c = s_xi[132 + half*3];
        float mx = fmaxf(a, fmaxf(b, c));
        float ea = fexp(a-mx), eb = fexp(b-mx), ec = fexp(c-mx);
        float s = frcp(ea+eb+ec);
        s_rm[half][0] = ea*s; s_rm[half][1] = eb*s; s_rm[half][2] = ec*s;
      }
    }
    __syncthreads();
    // ---- S2: per-half softmax + rw + read vector; h store for deferred logits ----
    if (t < 128) {
      int half = t >> 6, lane = t & 63;
      float rwv = 0.f;
      if (lane < 16) {
        float x = s_sim[half][lane] * frcp((s_norm[half][lane] + DELTAF)*(s_rkn[half] + DELTAF)) * s_rs[half];
        float mx = x;
        mx = fmaxf(mx, __shfl_xor(mx,1)); mx = fmaxf(mx, __shfl_xor(mx,2));
        mx = fmaxf(mx, __shfl_xor(mx,4)); mx = fmaxf(mx, __shfl_xor(mx,8));
        float ex = fexp(x - mx);
        float sm = ex;
        sm += __shfl_xor(sm,1); sm += __shfl_xor(sm,2); sm += __shfl_xor(sm,4); sm += __shfl_xor(sm,8);
        float cw = ex * frcp(sm);
        rwv = s_rm[half][0]*s_bw[half][lane] + s_rm[half][1]*s_fw[half][lane] + s_rm[half][2]*cw;
        s_rw[half][lane] = rwv;
      }
      float a = 0.f;
#pragma unroll
      for (int m = 0; m < 16; ++m) a = fmaf(__shfl(rwv, m), s_mem[half][m][t & 63], a);
      s_r12[half*64 + (t&63)] = a;
      r12h[it*256 + half*64 + (t&63)] = a;
    } else if (t < 256) {
      r12h[it*256 + t] = s_h[t - 128];
    }
    __syncthreads();
  }
}

// ---------------- deferred logits ----------------
__global__ void logits_kernel(
    const float* __restrict__ r2oW, const float* __restrict__ r2ob,
    const float* __restrict__ outW, const float* __restrict__ outb,
    const float* __restrict__ r12h, float* __restrict__ out)
{
  __shared__ __align__(16) float s_in[128];
  __shared__ __align__(16) float s_oh[128];
  const int it = blockIdx.x, t = threadIdx.x;
  if (t < 128) s_in[t] = r12h[it*256 + t];
  __syncthreads();
  if (t < 128) {
    float o = r2ob[t] + dotgf(r2oW + (size_t)t*128, s_in, 32);
    s_oh[t] = o + r12h[it*256 + 128 + t];
  }
  __syncthreads();
  if (t < 138) {
    out[it*138 + t] = outb[t] + dotgf(outW + (size_t)t*128, s_oh, 32);
  }
}

extern "C" void kernel_launch(void* const* d_in, const int* in_sizes, int n_in,
                              void* d_out, int out_size, void* d_ws, size_t ws_size,
                              hipStream_t stream) {
  (void)in_sizes; (void)n_in; (void)out_size; (void)ws_size;
  const float* emb0   = (const float*)d_in[0];
  const float* emb1   = (const float*)d_in[1];
  const float* emb2   = (const float*)d_in[2];
  const float* e1_Wih = (const float*)d_in[3];
  const float* e1_Whh = (const float*)d_in[4];
  const float* e1_bih = (const float*)d_in[5];
  const float* e1_bhh = (const float*)d_in[6];
  const float* e1_iW  = (const float*)d_in[7];
  const float* e1_ib  = (const float*)d_in[8];
  const float* e2_Wih = (const float*)d_in[9];
  const float* e2_Whh = (const float*)d_in[10];
  const float* e2_bih = (const float*)d_in[11];
  const float* e2_bhh = (const float*)d_in[12];
  const float* e2_iW  = (const float*)d_in[13];
  const float* e2_ib  = (const float*)d_in[14];
  const float* dWih   = (const float*)d_in[15];
  const float* dWhh   = (const float*)d_in[16];
  const float* dbih   = (const float*)d_in[17];
  const float* dbhh   = (const float*)d_in[18];
  const float* ifwW   = (const float*)d_in[19];
  const float* ifwb   = (const float*)d_in[20];
  const float* r2oW   = (const float*)d_in[21];
  const float* r2ob   = (const float*)d_in[22];
  const float* outW   = (const float*)d_in[23];
  const float* outb   = (const float*)d_in[24];
  const int* seq1     = (const int*)d_in[25];
  const int* seq2     = (const int*)d_in[26];
  const int* seq3     = (const int*)d_in[27];

  float* ws   = (float*)d_ws;
  float* giE1 = ws;                    // 512*192 = 98304
  float* giE2 = giE1 + 98304;          // 98304 (contiguous with giE1)
  float* giEd = giE2 + 98304;          // 65*384 = 24960
  float* st   = giEd + 24960;          // 2*1440 = 2880
  float* r12h = st + 2880;             // 65*256 = 16640
  float* pkw  = r12h + 16640;          // 33280 u32 packed (dec Whh + ifw)

  prep_enc<<<512, 192, 0, stream>>>(emb0, seq1, e1_Wih, e1_bih, giE1);
  prep_enc<<<512, 192, 0, stream>>>(emb1, seq2, e2_Wih, e2_bih, giE2);
  prep_dec<<<65, 384, 0, stream>>>(emb2, seq3, dWih, dbih, giEd);
  pack_weights<<<(33280 + 255) / 256, 256, 0, stream>>>(dWhh, ifwW, pkw);
  enc_kernel<<<2, 512, 0, stream>>>(e1_Wih, e1_Whh, e1_bhh, e1_iW, e1_ib,
                                    e2_Wih, e2_Whh, e2_bhh, e2_iW, e2_ib, giE1, st);
  dec_kernel<<<1, 512, 0, stream>>>(dbhh, ifwb, dWih, giEd, st, pkw, r12h);
  logits_kernel<<<65, 256, 0, stream>>>(r2oW, r2ob, outW, outb, r12h, (float*)d_out);
}

// Round 15
// 2525.948 us; speedup vs baseline: 1.0730x; 1.0730x over previous
//
#include <hip/hip_runtime.h>
#include <hip/hip_bf16.h>
#include <stdint.h>

typedef uint32_t u32;

#define DELTAF 1e-6f

__device__ __forceinline__ float bl(u32 u) { return __uint_as_float(u << 16); }
__device__ __forceinline__ float bh(u32 u) { return __uint_as_float(u & 0xffff0000u); }

// ---- fast transcendentals (f32 in/out, ~1e-7 rel err; deterministic) ----
__device__ __forceinline__ float fexp(float x) { return __builtin_amdgcn_exp2f(x * 1.4426950408889634f); }
__device__ __forceinline__ float frcp(float x) { return __builtin_amdgcn_rcpf(x); }
__device__ __forceinline__ float fsig(float x) { return frcp(1.f + fexp(-x)); }
__device__ __forceinline__ float ftanh(float x) {
  float xx = fminf(fmaxf(x, -15.f), 15.f);
  float t = __builtin_amdgcn_exp2f(xx * 2.8853900817779268f);  // e^(2x)
  return (t - 1.f) * frcp(t + 1.f);
}
__device__ __forceinline__ float softplusf(float x) { return fmaxf(x, 0.f) + log1pf(expf(-fabsf(x))); }

// f32 -> bf16 bits, RNE
__device__ __forceinline__ u32 f2b(float f) {
  u32 b = __float_as_uint(f);
  return (b + 0x7fffu + ((b >> 16) & 1u)) >> 16;
}
__device__ __forceinline__ u32 pk2(float a, float b) { return f2b(a) | (f2b(b) << 16); }

// ---- DPP reduction helpers (VALU-only) ----
template<int CTRL>
__device__ __forceinline__ float dppf(float v) {
  return __int_as_float(__builtin_amdgcn_update_dpp(0, __float_as_int(v), CTRL, 0xf, 0xf, true));
}
__device__ __forceinline__ float dsum16(float v) {
  v += dppf<0x128>(v); v += dppf<0x124>(v); v += dppf<0x122>(v); v += dppf<0x121>(v);
  return v;
}
__device__ __forceinline__ float dmax16(float v) {
  v = fmaxf(v, dppf<0x128>(v)); v = fmaxf(v, dppf<0x124>(v));
  v = fmaxf(v, dppf<0x122>(v)); v = fmaxf(v, dppf<0x121>(v));
  return v;
}
__device__ __forceinline__ float dsum4(float v) {
  v += dppf<0xB1>(v); v += dppf<0x4E>(v);
  return v;
}
__device__ __forceinline__ float rdlane(float v, int lane) {
  return __int_as_float(__builtin_amdgcn_readlane(__float_as_int(v), lane));
}

// load 64 consecutive f32 -> bf16 RNE, pack into 32 u32 (registers)
__device__ __forceinline__ void ldrow64pk(u32* w, const float* p) {
  const float4* q = (const float4*)p;
#pragma unroll
  for (int i = 0; i < 16; ++i) {
    float4 v = q[i];
    w[2*i]   = pk2(v.x, v.y);
    w[2*i+1] = pk2(v.z, v.w);
  }
}

// load 128 consecutive f32 -> bf16 RNE, pack pairs into 64 u32
__device__ __forceinline__ void ldrow128pk(u32* w, const float* p) {
  const float4* q = (const float4*)p;
#pragma unroll
  for (int i = 0; i < 32; ++i) {
    float4 v = q[i];
    w[2*i]   = pk2(v.x, v.y);
    w[2*i+1] = pk2(v.z, v.w);
  }
}

// 64-long dot, packed bf16 weights (32 u32), x from LDS (broadcast reads)
__device__ __forceinline__ float dotp64(const u32* w, const float* x) {
  float a0 = 0.f, a1 = 0.f;
#pragma unroll
  for (int i = 0; i < 8; ++i) {
    float4 v0 = ((const float4*)x)[2*i+0];
    float4 v1 = ((const float4*)x)[2*i+1];
    u32 p0 = w[4*i+0], q0 = w[4*i+1], p1 = w[4*i+2], q1 = w[4*i+3];
    a0 = fmaf(bl(p0), v0.x, a0); a0 = fmaf(bh(p0), v0.y, a0);
    a0 = fmaf(bl(q0), v0.z, a0); a0 = fmaf(bh(q0), v0.w, a0);
    a1 = fmaf(bl(p1), v1.x, a1); a1 = fmaf(bh(p1), v1.y, a1);
    a1 = fmaf(bl(q1), v1.z, a1); a1 = fmaf(bh(q1), v1.w, a1);
  }
  return a0 + a1;
}

// 128-long dot, packed bf16 weights in regs, x from LDS
__device__ __forceinline__ float dotp128(const u32* w, const float* x) {
  float a0 = 0.f, a1 = 0.f, a2 = 0.f, a3 = 0.f;
#pragma unroll
  for (int i = 0; i < 8; ++i) {
    float4 v0 = ((const float4*)x)[4*i+0];
    float4 v1 = ((const float4*)x)[4*i+1];
    float4 v2 = ((const float4*)x)[4*i+2];
    float4 v3 = ((const float4*)x)[4*i+3];
    u32 p0 = w[8*i+0], q0 = w[8*i+1], p1 = w[8*i+2], q1 = w[8*i+3];
    u32 p2 = w[8*i+4], q2 = w[8*i+5], p3 = w[8*i+6], q3 = w[8*i+7];
    a0 = fmaf(bl(p0), v0.x, a0); a0 = fmaf(bh(p0), v0.y, a0);
    a0 = fmaf(bl(q0), v0.z, a0); a0 = fmaf(bh(q0), v0.w, a0);
    a1 = fmaf(bl(p1), v1.x, a1); a1 = fmaf(bh(p1), v1.y, a1);
    a1 = fmaf(bl(q1), v1.z, a1); a1 = fmaf(bh(q1), v1.w, a1);
    a2 = fmaf(bl(p2), v2.x, a2); a2 = fmaf(bh(p2), v2.y, a2);
    a2 = fmaf(bl(q2), v2.z, a2); a2 = fmaf(bh(q2), v2.w, a2);
    a3 = fmaf(bl(p3), v3.x, a3); a3 = fmaf(bh(p3), v3.y, a3);
    a3 = fmaf(bl(q3), v3.z, a3); a3 = fmaf(bh(q3), v3.w, a3);
  }
  return (a0 + a1) + (a2 + a3);
}

// dot over 4*n4 elements, f32 weights streamed from global
__device__ __forceinline__ float dotgf(const float* row, const float* x, int n4) {
  float a = 0.f;
  for (int i = 0; i < n4; ++i) {
    float4 w = ((const float4*)row)[i];
    float4 xv = ((const float4*)x)[i];
    a = fmaf(w.x, xv.x, a);
    a = fmaf(w.y, xv.y, a);
    a = fmaf(w.z, xv.z, a);
    a = fmaf(w.w, xv.w, a);
  }
  return a;
}

// ---------------- prep kernels (gi_emb precompute) ----------------
__global__ void prep_enc(const float* __restrict__ emb, const int* __restrict__ seq,
                         const float* __restrict__ Wih, const float* __restrict__ bih,
                         float* __restrict__ giE)
{
  __shared__ __align__(16) float sx[64];
  const int it = blockIdx.x, t = threadIdx.x;
  if (t < 64) sx[t] = emb[(size_t)seq[it]*64 + t];
  __syncthreads();
  if (t < 192) giE[it*192 + t] = bih[t] + dotgf(Wih + (size_t)t*128, sx, 16);
}

__global__ void prep_dec(const float* __restrict__ emb2, const int* __restrict__ seq3,
                         const float* __restrict__ Wih, const float* __restrict__ bih,
                         float* __restrict__ giE)
{
  __shared__ __align__(16) float sx[64];
  const int it = blockIdx.x, t = threadIdx.x;
  const int tok = (it == 0) ? 136 : seq3[it-1];
  if (t < 64) sx[t] = emb2[(size_t)tok*64 + t];
  __syncthreads();
  if (t < 384) giE[it*384 + t] = bih[t] + dotgf(Wih + (size_t)t*192, sx, 16);
}

// ---------------- pack: dec Whh^T + ifw^T, bf16-pair [k2][r] ----------------
__global__ void pack_weights(const float* __restrict__ dWhh, const float* __restrict__ ifwW,
                             float* __restrict__ pk)
{
  const int i = blockIdx.x * 256 + threadIdx.x;
  u32* pku = (u32*)pk;
  if (i < 24576) {
    int r = i >> 6, k2 = i & 63;
    pku[k2*384 + r] = pk2(dWhh[r*128 + 2*k2], dWhh[r*128 + 2*k2 + 1]);
  } else if (i < 33280) {
    int p = i - 24576;
    int r = p >> 6, k2 = p & 63;
    pku[24576 + k2*136 + r] = pk2(ifwW[r*128 + 2*k2], ifwW[r*128 + 2*k2 + 1]);
  }
}

// ---------------- encoder: 512 sequential DNC steps, 1 block per encoder (R13) ----------------
// stout per encoder (1440 f32):
//  [0,64) h | [64,128) lr | [128,144) rw | [144,160) mem norms | [160,1184) mem | [1184,1440) link
__global__ __launch_bounds__(512) void enc_kernel(
    const float* __restrict__ Wih1, const float* __restrict__ Whh1, const float* __restrict__ bhh1,
    const float* __restrict__ iW1, const float* __restrict__ ib1,
    const float* __restrict__ Wih2, const float* __restrict__ Whh2, const float* __restrict__ bhh2,
    const float* __restrict__ iW2, const float* __restrict__ ib2,
    const float* __restrict__ giE_all, float* __restrict__ stout)
{
  __shared__ __align__(16) float s_giE[64*192];   // 64-step gi_emb chunk (49 KB)
  __shared__ __align__(16) float s_h[64];
  __shared__ __align__(16) float s_lr[64];
  __shared__ float s_gi[192];
  __shared__ float s_ghb[2][192];                 // gh pipeline (double buffer)
  __shared__ float s_xi[264];
  __shared__ float s_mem[16][65];                 // padded: conflict-free
  __shared__ float s_link[16][16];
  __shared__ float s_prec[2][16];
  __shared__ float s_rw[16], s_ww[16], s_usage[16];
  __shared__ float s_norm[16], s_sim[16], s_fw[16];
  __shared__ float s_rk[64], s_ev[64], s_wv[64];  // hoisted activations
  __shared__ float s_sc[8]; // 0:rs 1:ws 3:ag 4:wg 5..7:rm
  __shared__ float s_wkn, s_rkn;

  const int t = threadIdx.x;
  const int e = blockIdx.x;
  const float* Wih = e ? Wih2 : Wih1;
  const float* Whh = e ? Whh2 : Whh1;
  const float* bhh = e ? bhh2 : bhh1;
  const float* iW  = e ? iW2  : iW1;
  const float* ib  = e ? ib2  : ib1;
  const float* giE = giE_all + (size_t)e * 512 * 192;

  // register weights: wA = gi rows (t<192); w2 = xi rows (t<264) OR gh rows (264<=t<456)
  u32 wA[32], w2[32];
  float b2 = 0.f;
  if (t < 192) ldrow64pk(wA, Wih + (size_t)t*128 + 64);
  if (t < 264)      { ldrow64pk(w2, iW + (size_t)t*64);        b2 = ib[t]; }
  else if (t < 456) { ldrow64pk(w2, Whh + (size_t)(t-264)*64); b2 = bhh[t-264]; }

  if (t < 192) s_ghb[0][t] = bhh[t];     // h0 = 0 -> gh(step0) = bhh
  if (t < 64) { s_h[t] = 0.f; s_lr[t] = 0.f; }
  if (t < 16) {
    s_rw[t] = DELTAF; s_ww[t] = DELTAF; s_usage[t] = 0.f; s_norm[t] = 0.f;
    s_prec[0][t] = 0.f; s_prec[1][t] = 0.f;
  }
  for (int i = t; i < 1040; i += 512) { int m = i / 65, c = i % 65; s_mem[m][c] = 0.f; }
  if (t < 256) (&s_link[0][0])[t] = 0.f;
  __syncthreads();

  int pb = 0;
  for (int it = 0; it < 512; ++it) {
    // ---- chunk refill (8x total, only global access) ----
    if ((it & 63) == 0) {
      const float4* src = (const float4*)(giE + it*192);
      float4* dst = (float4*)s_giE;
      for (int i = t; i < 3072; i += 512) dst[i] = src[i];
      __syncthreads();
    }
    // ---- P1: gi GEMV (reg weights, lr broadcast from LDS) ----
    if (t < 192) s_gi[t] = s_giE[(it & 63)*192 + t] + dotp64(wA, s_lr);
    __syncthreads();
    // ---- P2: GRU combine (gh from pipeline; clip removed: |h|<=1 so CLIP(20) is a no-op) ----
    if (t < 64) {
      const float* ghb = s_ghb[it & 1];
      float r = fsig(s_gi[t] + ghb[t]);
      float z = fsig(s_gi[64+t] + ghb[64+t]);
      float n = ftanh(s_gi[128+t] + r*ghb[128+t]);
      s_h[t] = (1.f - z)*n + z*s_h[t];
    }
    __syncthreads();
    // ---- P3: xi GEMV (t<264) || gh GEMV for NEXT step (264<=t<456) ----
    if (t < 264)      s_xi[t] = b2 + dotp64(w2, s_h);
    else if (t < 456) s_ghb[(it + 1) & 1][t - 264] = b2 + dotp64(w2, s_h);
    __syncthreads();
    // ---- S1: write-key sim (16-lane DPP) + norms (16-lane DPP) + usage + scalars + hoists ----
    {
      int m = (t >> 4) & 15, l = t & 15;
      float p = 0.f;
#pragma unroll
      for (int i = 0; i < 4; ++i) {
        int el = l*4 + i;
        float wk = ftanh(s_xi[65+el]);
        p = fmaf(wk, s_mem[m][el], p);
      }
      p = dsum16(p);
      if (l == 0 && t < 256) s_sim[m] = p;   // raw dot; normalized later
    }
    if (t < 64) {
      s_ev[t] = fsig(s_xi[130+t]);
    } else if (t < 80) {                      // read-key norm (16 lanes x 4 elems)
      int l = t - 64;
      float q = 0.f;
#pragma unroll
      for (int i = 0; i < 4; ++i) { float v = ftanh(s_xi[l*4+i]); q = fmaf(v, v, q); }
      q = dsum16(q);
      if (t == 64) s_rkn = sqrtf(q);
    } else if (t < 96) {                      // write-key norm
      int l = t - 80;
      float q = 0.f;
#pragma unroll
      for (int i = 0; i < 4; ++i) { float v = ftanh(s_xi[65 + l*4+i]); q = fmaf(v, v, q); }
      q = dsum16(q);
      if (t == 80) s_wkn = sqrtf(q);
    } else if (t >= 192 && t < 208) {
      int j = t - 192;                        // usage update (prev ww, prev rw, this fg)
      float fg = fsig(s_xi[258]);
      float u = s_usage[j];
      u = u + (1.f - u) * s_ww[j];
      u = u * (1.f - fg * s_rw[j]);
      s_usage[j] = u;
    } else if (t == 208) s_sc[0] = softplusf(s_xi[64]);
    else if (t == 209) s_sc[1] = softplusf(s_xi[129]);
    else if (t == 210) s_sc[3] = fsig(s_xi[259]);
    else if (t == 211) s_sc[4] = fsig(s_xi[260]);
    else if (t == 212) {
      float a = s_xi[261], b = s_xi[262], c = s_xi[263];
      float mx = fmaxf(a, fmaxf(b, c));
      float ea = fexp(a-mx), eb = fexp(b-mx), ec = fexp(c-mx);
      float s = frcp(ea + eb + ec);
      s_sc[5] = ea*s; s_sc[6] = eb*s; s_sc[7] = ec*s;
    } else if (t >= 384 && t < 448) {
      int l = t - 384;                        // hoisted read-key tanh
      s_rk[l] = ftanh(s_xi[l]);
    } else if (t >= 448) {
      int l = t - 448;                        // hoisted write-vector tanh
      s_wv[l] = ftanh(s_xi[194+l]);
    }
    __syncthreads();
    // ---- S23: per-row redundant write-softmax/alloc (DPP); mem write (readlane); link+fw; prec ----
    {
      int row = t & 15;
      float x = s_sim[row] * frcp((s_norm[row] + DELTAF) * (s_wkn + DELTAF)) * s_sc[1];
      float mx = dmax16(x);
      float ex = fexp(x - mx);
      float sm = dsum16(ex);
      float wcw = ex * frcp(sm);
      float um = DELTAF + (1.f - DELTAF) * s_usage[row];
      float prod = 1.f;
#pragma unroll
      for (int j = 0; j < 16; ++j) {
        float v = DELTAF + (1.f - DELTAF) * s_usage[j];
        bool before = (v < um) || ((v == um) && (j < row));  // stable argsort order
        prod *= before ? v : 1.f;
      }
      float alloc = (1.f - um) * prod;
      float wwv = s_sc[4] * (s_sc[3]*alloc + (1.f - s_sc[3])*wcw);
      float S = dsum16(wwv);
      if (t < 16) s_ww[t] = wwv;              // for next step's usage update
      // memory write: m uniform per wave per q -> readlane broadcast (SALU)
#pragma unroll
      for (int q = 0; q < 2; ++q) {
        int idx = t + q*512;
        int m = idx >> 6, wi = idx & 63;
        float wwm = rdlane(wwv, m);
        s_mem[m][wi] = s_mem[m][wi] * (1.f - wwm * s_ev[wi]) + wwm * s_wv[wi];
      }
      if (t < 256) {                          // link + fw (waves 0..3)
        int i = t >> 4, j = t & 15;           // j == row
        float wwi = __shfl(wwv, i);           // per-lane gather (keep, 1 ds op)
        float lv = (i == j) ? 0.f
                 : ((1.f - wwi - wwv) * s_link[i][j] + wwi * s_prec[pb][j]);
        s_link[i][j] = lv;
        float p = dsum16(lv * s_rw[j]);
        if (j == 0) s_fw[i] = p;
      } else if (t < 272) {                   // precedence (wave 4, lanes 0..15)
        int j = t - 256;                      // == row
        s_prec[pb^1][j] = (1.f - S) * s_prec[pb][j] + wwv;
      }
    }
    __syncthreads();
    // ---- S45: wave-0 mega-phase: read sim+norm (quad DPP) + bw + softmax (DPP) + rw + lr ----
    if (t < 64) {
      int l = t;
      int r4 = l >> 2, seg = l & 3;
      float p = 0.f, q = 0.f;
#pragma unroll
      for (int i = 0; i < 16; ++i) {
        int el = seg*16 + i;
        float mv = s_mem[r4][el];
        p = fmaf(s_rk[el], mv, p);
        q = fmaf(mv, mv, q);
      }
      p = dsum4(p); q = dsum4(q);
      int row = l & 15;
      float simv  = __shfl(p, 4*row);          // fixed permutation gather
      float normv = sqrtf(__shfl(q, 4*row));
      float b = 0.f;                           // bw_row, partial over j
#pragma unroll
      for (int jj = 0; jj < 4; ++jj) {
        int j = (l >> 4)*4 + jj;
        b = fmaf(s_link[j][row], s_rw[j], b);
      }
      b += __shfl_xor(b,16); b += __shfl_xor(b,32);
      float x = simv * frcp((normv + DELTAF) * (s_rkn + DELTAF)) * s_sc[0];
      float mx = dmax16(x);
      float ex = fexp(x - mx);
      float sm = dsum16(ex);
      float cw = ex * frcp(sm);
      float rwv = s_sc[5]*b + s_sc[6]*s_fw[row] + s_sc[7]*cw;
      if (l < 16) { s_rw[l] = rwv; s_norm[l] = normv; }   // norm carried to next step
      float a = 0.f;
#pragma unroll
      for (int m = 0; m < 16; ++m) a = fmaf(rdlane(rwv, m), s_mem[m][l], a);
      s_lr[l] = a;
    }
    pb ^= 1;
    __syncthreads();
  }

  float* so = stout + (size_t)e * 1440;
  if (t < 64) { so[t] = s_h[t]; so[64+t] = s_lr[t]; }
  if (t < 16) { so[128+t] = s_rw[t]; so[144+t] = s_norm[t]; }
  for (int i = t; i < 1024; i += 512) { int m = i >> 6, c = i & 63; so[160+i] = s_mem[m][c]; }
  if (t < 256) so[1184+t] = (&s_link[0][0])[t];
}

// ---------------- decoder: 65 steps; Wih in regs, ifw in LDS, only Whh streamed (R13) ----------------
__global__ __launch_bounds__(512) void dec_kernel(
    const float* __restrict__ bhh, const float* __restrict__ ifwb,
    const float* __restrict__ dWih,
    const float* __restrict__ giE, const float* __restrict__ st,
    const float* __restrict__ pk, float* __restrict__ r12h)
{
  __shared__ u32 s_pIfw[8704];                 // ifw^T bf16-pair [k2][r] (34 KB)
  __shared__ __align__(16) float s_h[128];
  __shared__ __align__(16) float s_r12[128];
  __shared__ float s_gi[384], s_ghb[2][384], s_xi[136];
  __shared__ __align__(16) float s_mem[2][16][64];
  __shared__ float s_link[2][16][16];
  __shared__ float s_rw[2][16], s_norm[2][16];
  __shared__ float s_sim[2][16], s_fw[2][16], s_bw[2][16];
  __shared__ float s_rs[2], s_rkn[2];
  __shared__ float s_rm[2][3];
  __shared__ float s_bhh[384], s_ifwb[136];

  const int t = threadIdx.x;
  const u32* pWhh = (const u32*)pk;            // [k2*384 + r]
  const u32* pIfw = (const u32*)pk + 24576;    // [k2*136 + r]

  u32 w1[64];                                  // Wih-x row t (t<384), bf16
  if (t < 384) ldrow128pk(w1, dWih + (size_t)t*192 + 64);

  for (int i = t; i < 8704; i += 512) s_pIfw[i] = pIfw[i];
  if (t < 384) s_bhh[t]  = bhh[t];
  if (t < 136) s_ifwb[t] = ifwb[t];
  if (t < 64) {
    s_h[t]      = st[t];        s_h[64+t]   = st[1440+t];
    s_r12[t]    = st[64+t];     s_r12[64+t] = st[1440+64+t];
  }
  if (t < 16) {
    s_rw[0][t]   = st[128+t];   s_rw[1][t]   = st[1440+128+t];
    s_norm[0][t] = st[144+t];   s_norm[1][t] = st[1440+144+t];
  }
  for (int i = t; i < 1024; i += 512) {
    (&s_mem[0][0][0])[i] = st[160+i];
    (&s_mem[1][0][0])[i] = st[1440+160+i];
  }
  if (t < 256) {
    (&s_link[0][0][0])[t] = st[1184+t];
    (&s_link[1][0][0])[t] = st[1440+1184+t];
  }
  __syncthreads();

  // prologue: gh(step 0) = bhh + Whh . h0 (streamed)
  if (t < 384) {
    float a = 0.f;
#pragma unroll 8
    for (int k2 = 0; k2 < 64; ++k2) {
      u32 wp = pWhh[k2*384 + t];
      float2 xh = *(const float2*)&s_h[2*k2];
      a = fmaf(bl(wp), xh.x, fmaf(bh(wp), xh.y, a));
    }
    s_ghb[0][t] = s_bhh[t] + a;
  }
  __syncthreads();

  float gcur = (t < 384) ? giE[t] : 0.f;

  for (int it = 0; it < 65; ++it) {
    if (t < 384) {
      int nx = (it + 1 < 65) ? (it + 1) : 64;
      float gn = giE[nx*384 + t];
      s_gi[t] = gcur + dotp128(w1, s_r12);
      gcur = gn;
    }
    __syncthreads();
    if (t < 128) {
      const float* ghb = s_ghb[it & 1];
      float r = fsig(s_gi[t] + ghb[t]);
      float z = fsig(s_gi[128+t] + ghb[128+t]);
      float n = ftanh(s_gi[256+t] + r*ghb[256+t]);
      s_h[t] = (1.f - z)*n + z*s_h[t];
    }
    __syncthreads();
    if (t < 384) {
      float a = 0.f;
#pragma unroll 8
      for (int k2 = 0; k2 < 64; ++k2) {
        u32 wp = pWhh[k2*384 + t];
        float2 xh = *(const float2*)&s_h[2*k2];
        a = fmaf(bl(wp), xh.x, fmaf(bh(wp), xh.y, a));
      }
      s_ghb[(it + 1) & 1][t] = s_bhh[t] + a;
    } else {
      int r0 = t - 384;
      float c0 = 0.f;
#pragma unroll 8
      for (int k2 = 0; k2 < 64; ++k2) {
        u32 u = s_pIfw[k2*136 + r0];
        float2 xh = *(const float2*)&s_h[2*k2];
        c0 = fmaf(bl(u), xh.x, fmaf(bh(u), xh.y, c0));
      }
      s_xi[r0] = s_ifwb[r0] + c0;
      if (r0 < 8) {
        int r1 = 128 + r0;
        float c1 = 0.f;
#pragma unroll 8
        for (int k2 = 0; k2 < 64; ++k2) {
          u32 u = s_pIfw[k2*136 + r1];
          float2 xh = *(const float2*)&s_h[2*k2];
          c1 = fmaf(bl(u), xh.x, fmaf(bh(u), xh.y, c1));
        }
        s_xi[r1] = s_ifwb[r1] + c1;
      }
    }
    __syncthreads();
    {
      int half = t >> 8, u = t & 255;
      int m = u >> 4, l = u & 15;
      float p = 0.f;
#pragma unroll
      for (int i = 0; i < 4; ++i) {
        float rk = ftanh(s_xi[half*64 + l*4 + i]);
        p = fmaf(rk, s_mem[half][m][l*4+i], p);
      }
      p += __shfl_xor(p,1); p += __shfl_xor(p,2); p += __shfl_xor(p,4); p += __shfl_xor(p,8);
      if (l == 0) s_sim[half][m] = p;
      if (u < 64) {
        float v = ftanh(s_xi[half*64 + u]);
        float q = v*v;
        q += __shfl_xor(q,1); q += __shfl_xor(q,2); q += __shfl_xor(q,4);
        q += __shfl_xor(q,8); q += __shfl_xor(q,16); q += __shfl_xor(q,32);
        if (u == 0) s_rkn[half] = sqrtf(q);
      } else if (u < 80) {
        int i = u - 64;
        float a = 0.f;
#pragma unroll
        for (int j = 0; j < 16; ++j) a = fmaf(s_link[half][i][j], s_rw[half][j], a);
        s_fw[half][i] = a;
      } else if (u < 96) {
        int i = u - 80;
        float a = 0.f;
#pragma unroll
        for (int j = 0; j < 16; ++j) a = fmaf(s_link[half][j][i], s_rw[half][j], a);
        s_bw[half][i] = a;
      } else if (u == 96) {
        s_rs[half] = softplusf(s_xi[128 + half]);
        float a = s_xi[130 + half*3], b = s_xi[131 + half*3], c = s_xi[132 + half*3];
        float mx = fmaxf(a, fmaxf(b, c));
        float ea = fexp(a-mx), eb = fexp(b-mx), ec = fexp(c-mx);
        float s = frcp(ea+eb+ec);
        s_rm[half][0] = ea*s; s_rm[half][1] = eb*s; s_rm[half][2] = ec*s;
      }
    }
    __syncthreads();
    if (t < 128) {
      int half = t >> 6, lane = t & 63;
      float rwv = 0.f;
      if (lane < 16) {
        float x = s_sim[half][lane] * frcp((s_norm[half][lane] + DELTAF)*(s_rkn[half] + DELTAF)) * s_rs[half];
        float mx = x;
        mx = fmaxf(mx, __shfl_xor(mx,1)); mx = fmaxf(mx, __shfl_xor(mx,2));
        mx = fmaxf(mx, __shfl_xor(mx,4)); mx = fmaxf(mx, __shfl_xor(mx,8));
        float ex = fexp(x - mx);
        float sm = ex;
        sm += __shfl_xor(sm,1); sm += __shfl_xor(sm,2); sm += __shfl_xor(sm,4); sm += __shfl_xor(sm,8);
        float cw = ex * frcp(sm);
        rwv = s_rm[half][0]*s_bw[half][lane] + s_rm[half][1]*s_fw[half][lane] + s_rm[half][2]*cw;
        s_rw[half][lane] = rwv;
      }
      float a = 0.f;
#pragma unroll
      for (int m = 0; m < 16; ++m) a = fmaf(__shfl(rwv, m), s_mem[half][m][t & 63], a);
      s_r12[half*64 + (t&63)] = a;
      r12h[it*256 + half*64 + (t&63)] = a;
    } else if (t < 256) {
      r12h[it*256 + t] = s_h[t - 128];
    }
    __syncthreads();
  }
}

// ---------------- deferred logits ----------------
__global__ void logits_kernel(
    const float* __restrict__ r2oW, const float* __restrict__ r2ob,
    const float* __restrict__ outW, const float* __restrict__ outb,
    const float* __restrict__ r12h, float* __restrict__ out)
{
  __shared__ __align__(16) float s_in[128];
  __shared__ __align__(16) float s_oh[128];
  const int it = blockIdx.x, t = threadIdx.x;
  if (t < 128) s_in[t] = r12h[it*256 + t];
  __syncthreads();
  if (t < 128) {
    float o = r2ob[t] + dotgf(r2oW + (size_t)t*128, s_in, 32);
    s_oh[t] = o + r12h[it*256 + 128 + t];
  }
  __syncthreads();
  if (t < 138) {
    out[it*138 + t] = outb[t] + dotgf(outW + (size_t)t*128, s_oh, 32);
  }
}

extern "C" void kernel_launch(void* const* d_in, const int* in_sizes, int n_in,
                              void* d_out, int out_size, void* d_ws, size_t ws_size,
                              hipStream_t stream) {
  (void)in_sizes; (void)n_in; (void)out_size; (void)ws_size;
  const float* emb0   = (const float*)d_in[0];
  const float* emb1   = (const float*)d_in[1];
  const float* emb2   = (const float*)d_in[2];
  const float* e1_Wih = (const float*)d_in[3];
  const float* e1_Whh = (const float*)d_in[4];
  const float* e1_bih = (const float*)d_in[5];
  const float* e1_bhh = (const float*)d_in[6];
  const float* e1_iW  = (const float*)d_in[7];
  const float* e1_ib  = (const float*)d_in[8];
  const float* e2_Wih = (const float*)d_in[9];
  const float* e2_Whh = (const float*)d_in[10];
  const float* e2_bih = (const float*)d_in[11];
  const float* e2_bhh = (const float*)d_in[12];
  const float* e2_iW  = (const float*)d_in[13];
  const float* e2_ib  = (const float*)d_in[14];
  const float* dWih   = (const float*)d_in[15];
  const float* dWhh   = (const float*)d_in[16];
  const float* dbih   = (const float*)d_in[17];
  const float* dbhh   = (const float*)d_in[18];
  const float* ifwW   = (const float*)d_in[19];
  const float* ifwb   = (const float*)d_in[20];
  const float* r2oW   = (const float*)d_in[21];
  const float* r2ob   = (const float*)d_in[22];
  const float* outW   = (const float*)d_in[23];
  const float* outb   = (const float*)d_in[24];
  const int* seq1     = (const int*)d_in[25];
  const int* seq2     = (const int*)d_in[26];
  const int* seq3     = (const int*)d_in[27];

  float* ws   = (float*)d_ws;
  float* giE1 = ws;                    // 512*192 = 98304
  float* giE2 = giE1 + 98304;          // 98304 (contiguous with giE1)
  float* giEd = giE2 + 98304;          // 65*384 = 24960
  float* st   = giEd + 24960;          // 2*1440 = 2880
  float* r12h = st + 2880;             // 65*256 = 16640
  float* pkw  = r12h + 16640;          // 33280 u32 packed (dec Whh + ifw)

  prep_enc<<<512, 192, 0, stream>>>(emb0, seq1, e1_Wih, e1_bih, giE1);
  prep_enc<<<512, 192, 0, stream>>>(emb1, seq2, e2_Wih, e2_bih, giE2);
  prep_dec<<<65, 384, 0, stream>>>(emb2, seq3, dWih, dbih, giEd);
  pack_weights<<<(33280 + 255) / 256, 256, 0, stream>>>(dWhh, ifwW, pkw);
  enc_kernel<<<2, 512, 0, stream>>>(e1_Wih, e1_Whh, e1_bhh, e1_iW, e1_ib,
                                    e2_Wih, e2_Whh, e2_bhh, e2_iW, e2_ib, giE1, st);
  dec_kernel<<<1, 512, 0, stream>>>(dbhh, ifwb, dWih, giEd, st, pkw, r12h);
  logits_kernel<<<65, 256, 0, stream>>>(r2oW, r2ob, outW, outb, r12h, (float*)d_out);
}